// Round 4
// baseline (21644.757 us; speedup 1.0000x reference)
//
#include <hip/hip_runtime.h>
#include <cstdint>
#include <cstddef>

// GRU 3-layer, B=128 T=512 H=512, fp32 in/out.
// R6 = R5 design, register-disciplined:
//  - 48 WGs = 3 layers x 16 col-blocks (32 gate-cols each).
//  - W_ih half (k<512) in LDS (96 KB), W_hh half in REGISTERS (192 VGPR).
//  - NO global barrier: per-layer flags (own>=s, lower>=s+1, upper>=s-3)
//    over a 4-slot h ring; 3 loosely-coupled 16-WG convoys.
//  - h exchanged fragment-PACKED: reads wave-contiguous dwordx4; writes
//    staged via LDS then coalesced 8B agent-atomic stores. All h traffic
//    relaxed-agent (sc0 sc1), zero cache-maintenance ops in the loop.
//  - R6 changes: 8-frag (32 VGPR) load chunks w/ 2-deep ping-pong (peak
//    ~400 VGPR, no spill) + sched_barrier(0) pins prefetch issue points.

#define B_ 128
#define T_ 512
#define H_ 512
#define NWG 48
#define THREADS 256
#define RING 4

typedef _Float16 half8_t __attribute__((ext_vector_type(8)));
typedef float f32x4 __attribute__((ext_vector_type(4)));
typedef unsigned long long u64;
typedef union { u64 u[2]; half8_t h; } fragu;

// ws layout (bytes):
//        0 : flags[48], stride 128 B
//    16384 : biases [3][4][512] f32
//    40960 : hpack [3][RING][65536 halves] = 1.5 MB (fragment-packed h ring)
//  1613824 : W16L [48][49152] f16 (LDS images, ih half)
//  6332416 : W16R [48][49152] f16 (register images, hh half)
#define WS_BIAS 16384
#define WS_H    40960
#define WS_WL   1613824
#define WS_WR   6332416

#define MFMA(a, b, c) __builtin_amdgcn_mfma_f32_16x16x32_f16(a, b, c, 0, 0, 0)

// LLC-coherent (agent-scope relaxed) accesses: sc0 sc1, no cache maintenance.
__device__ __forceinline__ u64 llc_ld8(const _Float16* __restrict__ p) {
  return __hip_atomic_load((const u64*)p, __ATOMIC_RELAXED, __HIP_MEMORY_SCOPE_AGENT);
}
__device__ __forceinline__ void llc_st8(u64* __restrict__ p, u64 v) {
  __hip_atomic_store(p, v, __ATOMIC_RELAXED, __HIP_MEMORY_SCOPE_AGENT);
}

__device__ __forceinline__ half8_t ld_h8(const _Float16* __restrict__ p) {
  return *(const half8_t* __restrict__)p;
}
__device__ __forceinline__ half8_t ld_f8(const float* __restrict__ p) {
  const float4 u = *(const float4* __restrict__)p;
  const float4 v = *(const float4* __restrict__)(p + 4);
  half8_t a = { (_Float16)u.x, (_Float16)u.y, (_Float16)u.z, (_Float16)u.w,
                (_Float16)v.x, (_Float16)v.y, (_Float16)v.z, (_Float16)v.w };
  return a;
}

__global__ void zero_ws(int* __restrict__ ws) {
  int i = blockIdx.x * 256 + threadIdx.x;
  if (i < 403456) ws[i] = 0;   // flags + biases + hpack ring
}

__global__ void pack_b(const float* __restrict__ bi0, const float* __restrict__ bh0,
                       const float* __restrict__ bi1, const float* __restrict__ bh1,
                       const float* __restrict__ bi2, const float* __restrict__ bh2,
                       float* __restrict__ biases) {
  int idx = blockIdx.x * 256 + threadIdx.x;
  if (idx >= 1536) return;
  int l = idx >> 9, j = idx & 511;
  const float* bi = l == 0 ? bi0 : (l == 1 ? bi1 : bi2);
  const float* bh = l == 0 ? bh0 : (l == 1 ? bh1 : bh2);
  biases[(l*4+0)*512 + j] = bi[j] + bh[j];
  biases[(l*4+1)*512 + j] = bi[512+j] + bh[512+j];
  biases[(l*4+2)*512 + j] = bi[1024+j];
  biases[(l*4+3)*512 + j] = bh[1024+j];
}

// LDS image (e<49152): e = (((kb*3+gate)*2+ct)*64+lane)*8+el, kb 0..15 (ih half)
// REG image (e>=49152): e2 = (ct*64+lane)*384 + (gate*16+kb2)*8 + el (hh half)
// col=lane&15, q=lane>>4; j = wgG*32 + ct*16 + col; row = gate*512 + j;
// k = kb*32 + q*8 + el.
__global__ void pack_w(const float* __restrict__ Wih0, const float* __restrict__ Whh0,
                       const float* __restrict__ Wih1, const float* __restrict__ Whh1,
                       const float* __restrict__ Wih2, const float* __restrict__ Whh2,
                       _Float16* __restrict__ W16L, _Float16* __restrict__ W16R) {
  const int e = blockIdx.x * 256 + threadIdx.x;      // 0..98303
  const int bx = blockIdx.y;                          // 0..47
  const int l = bx >> 4, wgG = bx & 15;
  const float* Wih = l == 0 ? Wih0 : (l == 1 ? Wih1 : Wih2);
  const float* Whh = l == 0 ? Whh0 : (l == 1 ? Whh1 : Whh2);
  if (e < 49152) {
    const int el = e & 7;
    const int lane = (e >> 3) & 63;
    const int ctl = (e >> 9) & 1;
    const int gate = (e >> 10) % 3;
    const int kb = e / 3072;
    const int col = lane & 15, q = lane >> 4;
    const int j = wgG * 32 + ctl * 16 + col;
    const int row = gate * 512 + j;
    const int k = kb * 32 + q * 8 + el;
    W16L[(size_t)bx * 49152 + e] = (_Float16)Wih[row * 512 + k];
  } else {
    const int e2 = e - 49152;
    const int el = e2 & 7;
    const int kb2 = (e2 >> 3) & 15;
    const int gate = (e2 >> 7) % 3;        // works because 384 = 3*128
    const int lane = (e2 / 384) & 63;
    const int ctl = e2 / 24576;
    const int col = lane & 15, q = lane >> 4;
    const int j = wgG * 32 + ctl * 16 + col;
    const int row = gate * 512 + j;
    const int k = kb2 * 32 + q * 8 + el;
    W16R[(size_t)bx * 49152 + e2] = (_Float16)Whh[row * 512 + k];
  }
}

__global__ void __launch_bounds__(THREADS, 1)
gru_main(const float* __restrict__ x, float* __restrict__ out,
         int* __restrict__ bar, const float* __restrict__ biases,
         _Float16* __restrict__ hpk, const _Float16* __restrict__ W16L,
         const _Float16* __restrict__ W16R) {
  extern __shared__ _Float16 lds[];      // 49152 W + 4096 hstage = 106496 B
  _Float16* hstage = lds + 49152;
  const int tid = threadIdx.x;
  const int lane = tid & 63;
  const int wave = tid >> 6;
  const int bx = blockIdx.x;
  const int layer = bx >> 4;
  const int wgG = bx & 15;
  const int mh = wave >> 1;              // m-half (rows 0-63 / 64-127)
  const int ct = wave & 1;               // col-tile (16 cols each)
  int* __restrict__ flags = bar;         // flag i at +i*32 ints (128 B apart)

  { // stage LDS weights (ih half, fragment-ordered)
    const int* __restrict__ s4 = (const int*)(W16L + (size_t)bx * 49152);
    int* d4 = (int*)lds;
    for (int i = tid; i < 24576; i += THREADS) d4[i] = s4[i];
  }

  // hh-half weights -> registers (192 VGPR), resident across all steps
  fragu whh[3][16];
  { const _Float16* __restrict__ wr = W16R + (size_t)bx * 49152 + (ct * 64 + lane) * 384;
    #pragma unroll
    for (int g3 = 0; g3 < 3; ++g3)
      #pragma unroll
      for (int k = 0; k < 16; ++k) {
        const u64* p = (const u64*)(wr + (g3 * 16 + k) * 8);
        whh[g3][k].u[0] = p[0];
        whh[g3][k].u[1] = p[1];
      }
  }
  __syncthreads();

  const int col = lane & 15;
  const int q = lane >> 4;
  const int j = wgG * 32 + ct * 16 + col;
  const float b_r  = biases[(layer*4+0)*512 + j];
  const float b_z  = biases[(layer*4+1)*512 + j];
  const float b_ni = biases[(layer*4+2)*512 + j];
  const float b_nh = biases[(layer*4+3)*512 + j];

  const int mtb = mh * 4;                // 4 m-tiles per wave

  float hprev[4][4];
  #pragma unroll
  for (int m = 0; m < 4; ++m)
    #pragma unroll
    for (int i = 0; i < 4; ++i) hprev[m][i] = 0.f;

// load one chunk: 2 kb x 4 m = 8 frags = 32 VGPRs. CI in 0..7 selects kb pair.
#define LOADC(DST, BASE, CI) do { \
  _Pragma("unroll") for (int kk_ = 0; kk_ < 2; ++kk_) \
    _Pragma("unroll") for (int m_ = 0; m_ < 4; ++m_) { \
      const _Float16* p_ = (BASE) + ((mtb + m_) * 16 + ((CI) * 2 + kk_)) * 512 + lane * 8; \
      (DST)[kk_ * 4 + m_].u[0] = llc_ld8(p_); \
      (DST)[kk_ * 4 + m_].u[1] = llc_ld8(p_ + 4); } \
} while (0)

  for (int s = 0; s < T_; ++s) {
    // ---- wait phase (per-layer flags; no global barrier) ----
    if (s > 0 && tid < 16) {
      while (__hip_atomic_load(flags + (layer * 16 + tid) * 32,
                               __ATOMIC_RELAXED, __HIP_MEMORY_SCOPE_AGENT) < s)
        __builtin_amdgcn_s_sleep(1);
    }
    if (layer > 0 && tid >= 16 && tid < 32) {
      while (__hip_atomic_load(flags + ((layer - 1) * 16 + (tid - 16)) * 32,
                               __ATOMIC_RELAXED, __HIP_MEMORY_SCOPE_AGENT) < s + 1)
        __builtin_amdgcn_s_sleep(1);
    }
    if (layer < 2 && s >= RING && tid >= 32 && tid < 48) {
      while (__hip_atomic_load(flags + ((layer + 1) * 16 + (tid - 32)) * 32,
                               __ATOMIC_RELAXED, __HIP_MEMORY_SCOPE_AGENT) < s - (RING - 1))
        __builtin_amdgcn_s_sleep(1);
    }
    __syncthreads();

    const _Float16* __restrict__ hOwn =
        hpk + ((size_t)(layer * RING + ((s - 1) & (RING - 1))) << 16);
    _Float16* __restrict__ hWr =
        hpk + ((size_t)(layer * RING + (s & (RING - 1))) << 16);

    const f32x4 zero4 = {0.f, 0.f, 0.f, 0.f};
    f32x4 aR[4], aZ[4], aNI[4], aNH[4];
    #pragma unroll
    for (int m = 0; m < 4; ++m) { aR[m]=zero4; aZ[m]=zero4; aNI[m]=zero4; aNH[m]=zero4; }

    fragu po[2][8];   // own-h ping-pong chunks (phase 2 operand)

    // ---- phase 1: k<512, A = x (layer 0) or h_{l-1}(t) ----
    if (layer == 0) {
      LOADC(po[0], hOwn, 0);                 // own-h chunk 0 early
      __builtin_amdgcn_sched_barrier(0);
      const float* __restrict__ xb = x + (size_t)s * H_ + (q << 3);
      #pragma unroll 4
      for (int kb = 0; kb < 16; ++kb) {
        half8_t a[4];
        #pragma unroll
        for (int m = 0; m < 4; ++m)
          a[m] = ld_f8(xb + (size_t)((mtb + m) * 16 + col) * (T_ * H_) + kb * 32);
        const half8_t br = ld_h8(lds + ((kb * 3 + 0) * 2 + ct) * 512 + lane * 8);
        const half8_t bz = ld_h8(lds + ((kb * 3 + 1) * 2 + ct) * 512 + lane * 8);
        const half8_t bn = ld_h8(lds + ((kb * 3 + 2) * 2 + ct) * 512 + lane * 8);
        #pragma unroll
        for (int m = 0; m < 4; ++m) {
          aR[m]  = MFMA(a[m], br, aR[m]);
          aZ[m]  = MFMA(a[m], bz, aZ[m]);
          aNI[m] = MFMA(a[m], bn, aNI[m]);
        }
      }
    } else {
      const _Float16* __restrict__ hLo =
          hpk + ((size_t)((layer - 1) * RING + (s & (RING - 1))) << 16);
      fragu pl[2][8];
      LOADC(pl[0], hLo, 0);
      LOADC(pl[1], hLo, 1);
      LOADC(po[0], hOwn, 0);                 // own-h chunk 0 early
      __builtin_amdgcn_sched_barrier(0);
      #pragma unroll
      for (int c = 0; c < 8; ++c) {
        #pragma unroll
        for (int kk = 0; kk < 2; ++kk) {
          const int kb = c * 2 + kk;
          const half8_t br = ld_h8(lds + ((kb * 3 + 0) * 2 + ct) * 512 + lane * 8);
          const half8_t bz = ld_h8(lds + ((kb * 3 + 1) * 2 + ct) * 512 + lane * 8);
          const half8_t bn = ld_h8(lds + ((kb * 3 + 2) * 2 + ct) * 512 + lane * 8);
          #pragma unroll
          for (int m = 0; m < 4; ++m) {
            aR[m]  = MFMA(pl[c & 1][kk * 4 + m].h, br, aR[m]);
            aZ[m]  = MFMA(pl[c & 1][kk * 4 + m].h, bz, aZ[m]);
            aNI[m] = MFMA(pl[c & 1][kk * 4 + m].h, bn, aNI[m]);
          }
        }
        if (c < 6) { LOADC(pl[c & 1], hLo, c + 2); __builtin_amdgcn_sched_barrier(0); }
      }
    }

    // mask source for layer 2 (plain cached loads)
    float xm[4][4];
    if (layer == 2) {
      #pragma unroll
      for (int m = 0; m < 4; ++m)
        #pragma unroll
        for (int i = 0; i < 4; ++i)
          xm[m][i] = x[((size_t)((mtb + m) * 16 + q * 4 + i) * T_ + s) * H_ + j];
    }

    // ---- phase 2: k>=512, A = own h(t-1), B = whh from REGISTERS ----
    LOADC(po[1], hOwn, 1);
    __builtin_amdgcn_sched_barrier(0);
    #pragma unroll
    for (int c = 0; c < 8; ++c) {
      #pragma unroll
      for (int kk = 0; kk < 2; ++kk) {
        const int kb2 = c * 2 + kk;
        #pragma unroll
        for (int m = 0; m < 4; ++m) {
          aR[m]  = MFMA(po[c & 1][kk * 4 + m].h, whh[0][kb2].h, aR[m]);
          aZ[m]  = MFMA(po[c & 1][kk * 4 + m].h, whh[1][kb2].h, aZ[m]);
          aNH[m] = MFMA(po[c & 1][kk * 4 + m].h, whh[2][kb2].h, aNH[m]);
        }
      }
      if (c < 6) { LOADC(po[c & 1], hOwn, c + 2); __builtin_amdgcn_sched_barrier(0); }
    }

    // ---- epilogue: gates -> h; stage packed h in LDS ----
    #pragma unroll
    for (int m = 0; m < 4; ++m) {
      #pragma unroll
      for (int i = 0; i < 4; ++i) {
        const int brow = (mtb + m) * 16 + q * 4 + i;   // C/D: row = q*4 + reg
        const float rr = aR[m][i] + b_r;
        const float zz = aZ[m][i] + b_z;
        const float r = 1.f / (1.f + __expf(-rr));
        const float z = 1.f / (1.f + __expf(-zz));
        const float pre = (aNI[m][i] + b_ni) + r * (aNH[m][i] + b_nh);
        const float e2 = __expf(-2.f * fabsf(pre));
        float nt = (1.f - e2) / (1.f + e2);
        nt = (pre < 0.f) ? -nt : nt;
        float hn = (1.f - z) * nt + z * hprev[m][i];
        if (layer == 2) {
          const size_t oidx = ((size_t)brow * T_ + s) * H_ + j;
          hn = (xm[m][i] != 0.f) ? hn : 0.f;
          out[oidx] = hn;                  // plain store (flushed at kernel end)
        }
        hprev[m][i] = hn;
        // packed position: lane' = (q*4+i) + 16*(ct*2 + (col>>3)), el = col&7
        const int lane2 = (q * 4 + i) + 16 * (ct * 2 + (col >> 3));
        hstage[(mtb + m) * 512 + lane2 * 8 + (col & 7)] = (_Float16)hn;
      }
    }
    __syncthreads();

    // coalesced copy: LDS hstage -> hpack (8B agent-atomic stores)
    { const u64* __restrict__ srcc = (const u64*)hstage;
      u64* __restrict__ dst = (u64*)hWr;
      #pragma unroll
      for (int u0 = 0; u0 < 4; ++u0) {
        const int u = u0 * 256 + tid;
        const int mt = u >> 7, inner = u & 127;
        llc_st8(dst + (mt * 16 + wgG) * 128 + inner, srcc[u]);
      }
    }
    asm volatile("s_waitcnt vmcnt(0)" ::: "memory");   // each thread drains its stores
    __syncthreads();                                    // ... then WG-wide completion
    if (tid == 0)
      __hip_atomic_store(flags + bx * 32, s + 1,
                         __ATOMIC_RELAXED, __HIP_MEMORY_SCOPE_AGENT);
  }
#undef LOADC
}

extern "C" void kernel_launch(void* const* d_in, const int* in_sizes, int n_in,
                              void* d_out, int out_size, void* d_ws, size_t ws_size,
                              hipStream_t stream) {
  (void)in_sizes; (void)n_in; (void)out_size; (void)ws_size;
  const float* x    = (const float*)d_in[0];
  const float* Wih0 = (const float*)d_in[1];
  const float* Whh0 = (const float*)d_in[2];
  const float* bih0 = (const float*)d_in[3];
  const float* bhh0 = (const float*)d_in[4];
  const float* Wih1 = (const float*)d_in[5];
  const float* Whh1 = (const float*)d_in[6];
  const float* bih1 = (const float*)d_in[7];
  const float* bhh1 = (const float*)d_in[8];
  const float* Wih2 = (const float*)d_in[9];
  const float* Whh2 = (const float*)d_in[10];
  const float* bih2 = (const float*)d_in[11];
  const float* bhh2 = (const float*)d_in[12];

  char* ws = (char*)d_ws;
  int* bar = (int*)ws;
  float* biases = (float*)(ws + WS_BIAS);
  _Float16* hpk  = (_Float16*)(ws + WS_H);
  _Float16* W16L = (_Float16*)(ws + WS_WL);
  _Float16* W16R = (_Float16*)(ws + WS_WR);

  hipFuncSetAttribute((const void*)gru_main, hipFuncAttributeMaxDynamicSharedMemorySize, 106496);

  zero_ws<<<dim3(1577), dim3(256), 0, stream>>>((int*)ws);
  pack_b<<<dim3(6), dim3(256), 0, stream>>>(bih0, bhh0, bih1, bhh1, bih2, bhh2, biases);
  pack_w<<<dim3(384, 48), dim3(256), 0, stream>>>(Wih0, Whh0, Wih1, Whh1, Wih2, Whh2, W16L, W16R);
  gru_main<<<dim3(NWG), dim3(THREADS), 106496, stream>>>(x, (float*)d_out, bar, biases, hpk, W16L, W16R);
}

// Round 5
// 8985.634 us; speedup vs baseline: 2.4088x; 2.4088x over previous
//
#include <hip/hip_runtime.h>
#include <cstdint>
#include <cstddef>

// GRU 3-layer, B=128 T=512 H=512, fp32 in/out.
// R7 = R2's proven compute geometry (96 WGs = 3 layers x 32 col-blocks of 16
// gate-cols, 4 waves, all weights fp16 in LDS 96KB, fp32 hidden in regs)
// with the global barrier replaced by per-layer decoupled flags:
//   - phase A (k<512: x or h_{l-1}) gated on lower-layer flags >= s+1
//   - phase B (k>=512: own h)       gated on own-layer flags >= s
//   - ring backpressure             gated on upper-layer flags >= s-3
// over a 4-slot h ring. No cache-maintenance ops anywhere (h via relaxed
// agent-scope atomics, sc0 sc1). out stored NON-TEMPORALLY so x stays
// LLC-resident. Layers free-run +-2 steps; own-layer period = detect +
// phaseB only (phase A overlaps the wait).

#define B_ 128
#define T_ 512
#define H_ 512
#define NWG 96
#define THREADS 256
#define RING 4

typedef _Float16 half8_t __attribute__((ext_vector_type(8)));
typedef float f32x4 __attribute__((ext_vector_type(4)));
typedef unsigned long long u64;
typedef union { u64 u[2]; half8_t h; } fragu;

// ws layout (bytes):
//        0 : flags[96], stride 128 B (12288 B)
//    16384 : biases [3][4][512] f32 (24576 B)
//    40960 : h16 [3][RING][128*512] f16 = 1,572,864 B
//  1613824 : W16 [96][49152] f16 (LDS images, fragment-ordered) = 9,437,184 B
//  total 11,051,008 B (same end as R6, which launched OK)
#define WS_BIAS 16384
#define WS_H    40960
#define WS_W16  1613824

#define MFMA(a, b, c) __builtin_amdgcn_mfma_f32_16x16x32_f16(a, b, c, 0, 0, 0)

// LLC-coherent (agent-scope relaxed) accesses: sc0 sc1, no cache maintenance.
__device__ __forceinline__ u64 llc_ld8(const _Float16* __restrict__ p) {
  return __hip_atomic_load((const u64*)p, __ATOMIC_RELAXED, __HIP_MEMORY_SCOPE_AGENT);
}
__device__ __forceinline__ void llc_st2(_Float16* __restrict__ p, float v) {
  union { _Float16 f; unsigned short u; } cv; cv.f = (_Float16)v;
  __hip_atomic_store((unsigned short*)p, cv.u, __ATOMIC_RELAXED, __HIP_MEMORY_SCOPE_AGENT);
}

__device__ __forceinline__ half8_t ld_h8(const _Float16* __restrict__ p) {
  return *(const half8_t* __restrict__)p;
}
__device__ __forceinline__ half8_t ld_f8(const float* __restrict__ p) {
  const float4 u = *(const float4* __restrict__)p;
  const float4 v = *(const float4* __restrict__)(p + 4);
  half8_t a = { (_Float16)u.x, (_Float16)u.y, (_Float16)u.z, (_Float16)u.w,
                (_Float16)v.x, (_Float16)v.y, (_Float16)v.z, (_Float16)v.w };
  return a;
}

__global__ void zero_ws(int* __restrict__ ws) {
  int i = blockIdx.x * 256 + threadIdx.x;
  if (i < 403456) ws[i] = 0;   // flags + biases + h16 ring
}

__global__ void pack_b(const float* __restrict__ bi0, const float* __restrict__ bh0,
                       const float* __restrict__ bi1, const float* __restrict__ bh1,
                       const float* __restrict__ bi2, const float* __restrict__ bh2,
                       float* __restrict__ biases) {
  int idx = blockIdx.x * 256 + threadIdx.x;
  if (idx >= 1536) return;
  int l = idx >> 9, j = idx & 511;
  const float* bi = l == 0 ? bi0 : (l == 1 ? bi1 : bi2);
  const float* bh = l == 0 ? bh0 : (l == 1 ? bh1 : bh2);
  biases[(l*4+0)*512 + j] = bi[j] + bh[j];
  biases[(l*4+1)*512 + j] = bi[512+j] + bh[512+j];
  biases[(l*4+2)*512 + j] = bi[1024+j];
  biases[(l*4+3)*512 + j] = bh[1024+j];
}

// W16[bx][e]: e = (kb*3 + gate)*512 + lane*8 + el ; col=lane&15, q=lane>>4
// -> W[gate*512 + g*16+col][k], k = kb*32 + q*8 + el; k<512 -> W_ih else W_hh.
// (identical to R2's proven pack)
__global__ void pack_w(const float* __restrict__ Wih0, const float* __restrict__ Whh0,
                       const float* __restrict__ Wih1, const float* __restrict__ Whh1,
                       const float* __restrict__ Wih2, const float* __restrict__ Whh2,
                       _Float16* __restrict__ W16) {
  const int e = blockIdx.x * 256 + threadIdx.x;
  const int bxw = blockIdx.y;
  const int l = bxw >> 5, g = bxw & 31;
  const int kb = e / 1536;
  const int rem = e - kb * 1536;
  const int gate = rem >> 9;
  const int r2 = rem & 511;
  const int lane = r2 >> 3;
  const int el = r2 & 7;
  const int col = lane & 15, q = lane >> 4;
  const int k = kb * 32 + q * 8 + el;
  const int row = gate * 512 + g * 16 + col;
  const float* Wih = l == 0 ? Wih0 : (l == 1 ? Wih1 : Wih2);
  const float* Whh = l == 0 ? Whh0 : (l == 1 ? Whh1 : Whh2);
  const float v = (k < 512) ? Wih[row * 512 + k] : Whh[row * 512 + (k - 512)];
  W16[(size_t)bxw * 49152 + e] = (_Float16)v;
}

__global__ void __launch_bounds__(THREADS, 1)
gru_main(const float* __restrict__ x, float* __restrict__ out,
         int* __restrict__ bar, const float* __restrict__ biases,
         _Float16* __restrict__ h16, const _Float16* __restrict__ W16) {
  extern __shared__ _Float16 Wlds[];    // 49152 f16 = 96 KB
  const int tid = threadIdx.x;
  const int lane = tid & 63;
  const int wave = tid >> 6;
  const int bx = blockIdx.x;
  const int layer = bx >> 5;
  const int g = bx & 31;

  int* __restrict__ flags = bar;        // flag i at +i*32 ints (128 B apart)

  { // stage weights once; linear copy (image already fragment-ordered)
    const int* __restrict__ s4 = (const int*)(W16 + (size_t)bx * 49152);
    int* d4 = (int*)Wlds;
    for (int i = tid; i < 24576; i += THREADS) d4[i] = s4[i];
  }
  __syncthreads();

  const int col = lane & 15;
  const int q = lane >> 4;
  const int koff = q << 3;
  const int j = (g << 4) + col;
  const float b_r  = biases[(layer*4+0)*512 + j];
  const float b_z  = biases[(layer*4+1)*512 + j];
  const float b_ni = biases[(layer*4+2)*512 + j];
  const float b_nh = biases[(layer*4+3)*512 + j];

  const int mtb = wave * 2;             // 2 m-tiles per wave (4 waves)
  int rows[2];
  #pragma unroll
  for (int m = 0; m < 2; ++m) rows[m] = (mtb + m) * 16 + col;

  float hprev[2][4];
  #pragma unroll
  for (int m = 0; m < 2; ++m)
    #pragma unroll
    for (int i = 0; i < 4; ++i) hprev[m][i] = 0.f;

  const _Float16* __restrict__ WlB = Wlds + lane * 8;

  for (int s = 0; s < T_; ++s) {
    // ---- pre-A wait: lower layer published h_{l-1}(s) ----
    if (layer > 0 && tid < 32) {
      while (__hip_atomic_load(flags + ((layer - 1) * 32 + tid) * 32,
                               __ATOMIC_RELAXED, __HIP_MEMORY_SCOPE_AGENT) < s + 1)
        __builtin_amdgcn_s_sleep(1);
    }
    __syncthreads();
    asm volatile("" ::: "memory");

    const f32x4 zero4 = {0.f, 0.f, 0.f, 0.f};
    f32x4 aR[2], aZ[2], aNI[2], aNH[2];
    #pragma unroll
    for (int m = 0; m < 2; ++m) { aR[m]=zero4; aZ[m]=zero4; aNI[m]=zero4; aNH[m]=zero4; }

    // ---- phase A: k<512, A = x (layer 0) or h_{l-1}(s) ----
    if (layer == 0) {
      const float* __restrict__ xb = x + (size_t)s * H_ + koff;
      #pragma unroll 4
      for (int kb = 0; kb < 16; ++kb) {
        half8_t a[2];
        #pragma unroll
        for (int m = 0; m < 2; ++m)
          a[m] = ld_f8(xb + (size_t)rows[m] * (T_ * H_) + kb * 32);
        const _Float16* wb = WlB + kb * 1536;
        const half8_t br = ld_h8(wb);
        const half8_t bz = ld_h8(wb + 512);
        const half8_t bn = ld_h8(wb + 1024);
        #pragma unroll
        for (int m = 0; m < 2; ++m) {
          aR[m]  = MFMA(a[m], br, aR[m]);
          aZ[m]  = MFMA(a[m], bz, aZ[m]);
          aNI[m] = MFMA(a[m], bn, aNI[m]);
        }
      }
    } else {
      const _Float16* __restrict__ hin =
          h16 + (((size_t)((layer - 1) * RING + (s & (RING - 1)))) << 16) + koff;
      fragu ha[16][2];
      #pragma unroll
      for (int kb = 0; kb < 16; ++kb)
        #pragma unroll
        for (int m = 0; m < 2; ++m) {
          const _Float16* p = hin + rows[m] * H_ + kb * 32;
          ha[kb][m].u[0] = llc_ld8(p);
          ha[kb][m].u[1] = llc_ld8(p + 4);
        }
      #pragma unroll
      for (int kb = 0; kb < 16; ++kb) {
        const _Float16* wb = WlB + kb * 1536;
        const half8_t br = ld_h8(wb);
        const half8_t bz = ld_h8(wb + 512);
        const half8_t bn = ld_h8(wb + 1024);
        #pragma unroll
        for (int m = 0; m < 2; ++m) {
          aR[m]  = MFMA(ha[kb][m].h, br, aR[m]);
          aZ[m]  = MFMA(ha[kb][m].h, bz, aZ[m]);
          aNI[m] = MFMA(ha[kb][m].h, bn, aNI[m]);
        }
      }
    }

    // mask source for layer 2 (plain cached loads; overlaps the mid-wait)
    float xm[2][4];
    if (layer == 2) {
      #pragma unroll
      for (int m = 0; m < 2; ++m)
        #pragma unroll
        for (int i = 0; i < 4; ++i)
          xm[m][i] = x[((size_t)((mtb + m) * 16 + q * 4 + i) * T_ + s) * H_ + j];
    }

    // ---- mid wait: own h(s-1) ready; upper done with h(s-4) (ring slot) ----
    if (s > 0 && tid < 32) {
      while (__hip_atomic_load(flags + (layer * 32 + tid) * 32,
                               __ATOMIC_RELAXED, __HIP_MEMORY_SCOPE_AGENT) < s)
        __builtin_amdgcn_s_sleep(1);
    }
    if (layer < 2 && s >= RING && tid >= 32 && tid < 64) {
      while (__hip_atomic_load(flags + ((layer + 1) * 32 + (tid - 32)) * 32,
                               __ATOMIC_RELAXED, __HIP_MEMORY_SCOPE_AGENT) < s - (RING - 1))
        __builtin_amdgcn_s_sleep(1);
    }
    __syncthreads();
    asm volatile("" ::: "memory");

    // ---- phase B: k>=512, A = own h(s-1) ----
    const _Float16* __restrict__ hown =
        h16 + (((size_t)(layer * RING + ((s - 1) & (RING - 1)))) << 16) + koff;
    fragu hb[16][2];
    #pragma unroll
    for (int kb = 0; kb < 16; ++kb)
      #pragma unroll
      for (int m = 0; m < 2; ++m) {
        const _Float16* p = hown + rows[m] * H_ + kb * 32;
        hb[kb][m].u[0] = llc_ld8(p);
        hb[kb][m].u[1] = llc_ld8(p + 4);
      }
    #pragma unroll
    for (int kb = 16; kb < 32; ++kb) {
      const _Float16* wb = WlB + kb * 1536;
      const half8_t br = ld_h8(wb);
      const half8_t bz = ld_h8(wb + 512);
      const half8_t bn = ld_h8(wb + 1024);
      #pragma unroll
      for (int m = 0; m < 2; ++m) {
        aR[m]  = MFMA(hb[kb-16][m].h, br, aR[m]);
        aZ[m]  = MFMA(hb[kb-16][m].h, bz, aZ[m]);
        aNH[m] = MFMA(hb[kb-16][m].h, bn, aNH[m]);
      }
    }

    // ---- epilogue ----
    _Float16* __restrict__ hw =
        h16 + (((size_t)(layer * RING + (s & (RING - 1)))) << 16);
    #pragma unroll
    for (int m = 0; m < 2; ++m) {
      #pragma unroll
      for (int i = 0; i < 4; ++i) {
        const int brow = (mtb + m) * 16 + q * 4 + i;   // C/D: row = q*4 + reg
        const float rr = aR[m][i] + b_r;
        const float zz = aZ[m][i] + b_z;
        const float r = 1.f / (1.f + __expf(-rr));
        const float z = 1.f / (1.f + __expf(-zz));
        const float pre = (aNI[m][i] + b_ni) + r * (aNH[m][i] + b_nh);
        const float e2 = __expf(-2.f * fabsf(pre));
        float nt = (1.f - e2) / (1.f + e2);
        nt = (pre < 0.f) ? -nt : nt;
        float hn = (1.f - z) * nt + z * hprev[m][i];
        if (layer == 2) {
          const size_t oidx = ((size_t)brow * T_ + s) * H_ + j;
          hn = (xm[m][i] != 0.f) ? hn : 0.f;
          __builtin_nontemporal_store(hn, out + oidx);  // NT: don't evict x from LLC
        }
        hprev[m][i] = hn;
        llc_st2(hw + brow * H_ + j, hn);  // write-through to LLC
      }
    }

    // ---- publish: all h stores drained, then flag = s+1 ----
    asm volatile("s_waitcnt vmcnt(0)" ::: "memory");
    __syncthreads();
    if (tid == 0)
      __hip_atomic_store(flags + bx * 32, s + 1,
                         __ATOMIC_RELAXED, __HIP_MEMORY_SCOPE_AGENT);
  }
}

extern "C" void kernel_launch(void* const* d_in, const int* in_sizes, int n_in,
                              void* d_out, int out_size, void* d_ws, size_t ws_size,
                              hipStream_t stream) {
  (void)in_sizes; (void)n_in; (void)out_size; (void)ws_size;
  const float* x    = (const float*)d_in[0];
  const float* Wih0 = (const float*)d_in[1];
  const float* Whh0 = (const float*)d_in[2];
  const float* bih0 = (const float*)d_in[3];
  const float* bhh0 = (const float*)d_in[4];
  const float* Wih1 = (const float*)d_in[5];
  const float* Whh1 = (const float*)d_in[6];
  const float* bih1 = (const float*)d_in[7];
  const float* bhh1 = (const float*)d_in[8];
  const float* Wih2 = (const float*)d_in[9];
  const float* Whh2 = (const float*)d_in[10];
  const float* bih2 = (const float*)d_in[11];
  const float* bhh2 = (const float*)d_in[12];

  char* ws = (char*)d_ws;
  int* bar = (int*)ws;
  float* biases = (float*)(ws + WS_BIAS);
  _Float16* h16 = (_Float16*)(ws + WS_H);
  _Float16* W16 = (_Float16*)(ws + WS_W16);

  hipFuncSetAttribute((const void*)gru_main, hipFuncAttributeMaxDynamicSharedMemorySize, 98304);

  zero_ws<<<dim3(1577), dim3(256), 0, stream>>>((int*)ws);
  pack_b<<<dim3(6), dim3(256), 0, stream>>>(bih0, bhh0, bih1, bhh1, bih2, bhh2, biases);
  pack_w<<<dim3(192, 96), dim3(256), 0, stream>>>(Wih0, Whh0, Wih1, Whh1, Wih2, Whh2, W16);
  gru_main<<<dim3(NWG), dim3(THREADS), 98304, stream>>>(x, (float*)d_out, bar, biases, h16, W16);
}